// Round 2
// baseline (403.039 us; speedup 1.0000x reference)
//
#include <hip/hip_runtime.h>

// B=256, C=3, H=W=256, E=8
// out[b,c,h,w] = bilinear_sample(x[b,c], affine(theta_b, (h,w))), zero padding,
// align_corners=False. theta_b = smp_b * Wt[e] + bt[e], e = tsmp[b],
// smp_b = distr_flags[e]==1 ? nsmp[b] : usmp[b].
//
// R2: XCD-aware block swizzle (8 XCDs, 65536 blocks -> each XCD gets a
// contiguous chunk of (b,h) pairs so each batch's 768KB image stays in one
// XCD's private L2) + non-temporal output stores (output is never re-read;
// keep L2 capacity for the gather-serving input lines).

__global__ __launch_bounds__(256) void dataug_kernel(
    const float* __restrict__ x,
    const float* __restrict__ usmp,
    const float* __restrict__ nsmp,
    const float* __restrict__ Wt,
    const float* __restrict__ bt,
    const int*   __restrict__ tsmp,
    const int*   __restrict__ distr,
    float* __restrict__ out)
{
    constexpr int H = 256, W = 256, C = 3;
    constexpr int NXCD = 8;
    constexpr int NWG  = 256 * 256;          // B*H
    constexpr int CHUNK = NWG / NXCD;        // 8192

    // XCD swizzle: hardware round-robins blockIdx across XCDs; remap so each
    // XCD sees a contiguous run of (b,h). nwg % 8 == 0 -> bijective.
    const int bid = blockIdx.x;
    const int bh  = (bid & (NXCD - 1)) * CHUNK + (bid >> 3);

    const int b  = bh >> 8;     // / H
    const int h  = bh & 255;    // % H
    const int w  = threadIdx.x;

    // --- per-batch theta (block-uniform -> scalar loads) ---
    const int e = tsmp[b];
    const float smp = (distr[e] == 1) ? nsmp[b] : usmp[b];
    const float t0 = smp * Wt[e*6 + 0] + bt[e*6 + 0];
    const float t1 = smp * Wt[e*6 + 1] + bt[e*6 + 1];
    const float t2 = smp * Wt[e*6 + 2] + bt[e*6 + 2];
    const float t3 = smp * Wt[e*6 + 3] + bt[e*6 + 3];
    const float t4 = smp * Wt[e*6 + 4] + bt[e*6 + 4];
    const float t5 = smp * Wt[e*6 + 5] + bt[e*6 + 5];

    // --- affine grid (align_corners=False) ---
    const float xs = (2.0f * (float)w + 1.0f) / (float)W - 1.0f;
    const float ys = (2.0f * (float)h + 1.0f) / (float)H - 1.0f;
    const float gx = t0 * xs + t1 * ys + t2;
    const float gy = t3 * xs + t4 * ys + t5;

    // --- unnormalize to input pixel space ---
    const float ix = ((gx + 1.0f) * (float)W - 1.0f) * 0.5f;
    const float iy = ((gy + 1.0f) * (float)H - 1.0f) * 0.5f;

    const float ix0f = floorf(ix);
    const float iy0f = floorf(iy);
    const float wx1 = ix - ix0f, wx0 = 1.0f - wx1;
    const float wy1 = iy - iy0f, wy0 = 1.0f - wy1;

    const int ix0 = (int)ix0f, iy0 = (int)iy0f;
    const int ix1 = ix0 + 1,   iy1 = iy0 + 1;

    const bool vx0 = (ix0 >= 0) & (ix0 <= W - 1);
    const bool vx1 = (ix1 >= 0) & (ix1 <= W - 1);
    const bool vy0 = (iy0 >= 0) & (iy0 <= H - 1);
    const bool vy1 = (iy1 >= 0) & (iy1 <= H - 1);

    const int cx0 = min(max(ix0, 0), W - 1);
    const int cx1 = min(max(ix1, 0), W - 1);
    const int cy0 = min(max(iy0, 0), H - 1);
    const int cy1 = min(max(iy1, 0), H - 1);

    // fold validity into weights (equivalent to zeroing invalid taps)
    const float w00 = (vy0 && vx0) ? wy0 * wx0 : 0.0f;
    const float w01 = (vy0 && vx1) ? wy0 * wx1 : 0.0f;
    const float w10 = (vy1 && vx0) ? wy1 * wx0 : 0.0f;
    const float w11 = (vy1 && vx1) ? wy1 * wx1 : 0.0f;

    const int o00 = cy0 * W + cx0;
    const int o01 = cy0 * W + cx1;
    const int o10 = cy1 * W + cx0;
    const int o11 = cy1 * W + cx1;

    const size_t plane = (size_t)H * W;
    const float* img = x   + (size_t)b * C * plane;
    float*       og  = out + (size_t)b * C * plane + (size_t)h * W + w;

#pragma unroll
    for (int c = 0; c < C; ++c) {
        const float* p = img + (size_t)c * plane;
        float v = p[o00] * w00 + p[o01] * w01 + p[o10] * w10 + p[o11] * w11;
        __builtin_nontemporal_store(v, og + (size_t)c * plane);
    }
}

extern "C" void kernel_launch(void* const* d_in, const int* in_sizes, int n_in,
                              void* d_out, int out_size, void* d_ws, size_t ws_size,
                              hipStream_t stream)
{
    const float* x     = (const float*)d_in[0];
    const float* usmp  = (const float*)d_in[1];
    const float* nsmp  = (const float*)d_in[2];
    const float* Wt    = (const float*)d_in[3];
    const float* bt    = (const float*)d_in[4];
    const int*   tsmp  = (const int*)d_in[5];
    const int*   distr = (const int*)d_in[6];
    float* out = (float*)d_out;

    // B*H blocks of W threads
    dim3 grid(256 * 256);
    dim3 block(256);
    dataug_kernel<<<grid, block, 0, stream>>>(x, usmp, nsmp, Wt, bt, tsmp, distr, out);
}

// Round 3
// 398.024 us; speedup vs baseline: 1.0126x; 1.0126x over previous
//
#include <hip/hip_runtime.h>

// B=256, C=3, H=W=256, E=8
// out[b,c,h,w] = bilinear_sample(x[b,c], affine(theta_b, (h,w))), zero padding,
// align_corners=False. theta_b = smp_b * Wt[e] + bt[e], e = tsmp[b],
// smp_b = distr_flags[e]==1 ? nsmp[b] : usmp[b].
//
// R3: latency-bound fix -> 4 output rows per thread (4 independent bilinear
// gather chains, 48 loads in flight), amortized theta/addr setup.
// Row increments: d(ix)/d(row) = t1, d(iy)/d(row) = t4 (since W==H).
// Keep XCD swizzle (R2: FETCH 391->95 MB) + non-temporal stores.

__global__ __launch_bounds__(256) void dataug_kernel(
    const float* __restrict__ x,
    const float* __restrict__ usmp,
    const float* __restrict__ nsmp,
    const float* __restrict__ Wt,
    const float* __restrict__ bt,
    const int*   __restrict__ tsmp,
    const int*   __restrict__ distr,
    float* __restrict__ out)
{
    constexpr int H = 256, W = 256, C = 3;
    constexpr int ROWS = 4;                       // rows per thread
    constexpr int NXCD = 8;
    constexpr int NWG  = 256 * (256 / ROWS);      // 16384 blocks
    constexpr int CHUNK = NWG / NXCD;             // 2048

    const int bid = blockIdx.x;
    const int bh4 = (bid & (NXCD - 1)) * CHUNK + (bid >> 3);

    const int b  = bh4 >> 6;          // / (H/ROWS)
    const int h0 = (bh4 & 63) << 2;   // % (H/ROWS) * ROWS
    const int w  = threadIdx.x;

    // --- per-batch theta (block-uniform -> scalar loads) ---
    const int e = tsmp[b];
    const float smp = (distr[e] == 1) ? nsmp[b] : usmp[b];
    const float t0 = smp * Wt[e*6 + 0] + bt[e*6 + 0];
    const float t1 = smp * Wt[e*6 + 1] + bt[e*6 + 1];
    const float t2 = smp * Wt[e*6 + 2] + bt[e*6 + 2];
    const float t3 = smp * Wt[e*6 + 3] + bt[e*6 + 3];
    const float t4 = smp * Wt[e*6 + 4] + bt[e*6 + 4];
    const float t5 = smp * Wt[e*6 + 5] + bt[e*6 + 5];

    // --- affine grid (align_corners=False), row h0 ---
    const float xs = (2.0f * (float)w  + 1.0f) / (float)W - 1.0f;
    const float ys = (2.0f * (float)h0 + 1.0f) / (float)H - 1.0f;
    const float gx0 = t0 * xs + t1 * ys + t2;
    const float gy0 = t3 * xs + t4 * ys + t5;

    // unnormalized pixel coords for row h0; per-row step is (t1, t4)
    const float ix_base = ((gx0 + 1.0f) * (float)W - 1.0f) * 0.5f;
    const float iy_base = ((gy0 + 1.0f) * (float)H - 1.0f) * 0.5f;

    const size_t plane = (size_t)H * W;
    const float* img = x   + (size_t)b * C * plane;
    float*       ob  = out + (size_t)b * C * plane + (size_t)h0 * W + w;

#pragma unroll
    for (int r = 0; r < ROWS; ++r) {
        const float ix = ix_base + t1 * (float)r;
        const float iy = iy_base + t4 * (float)r;

        const float ix0f = floorf(ix);
        const float iy0f = floorf(iy);
        const float wx1 = ix - ix0f, wx0 = 1.0f - wx1;
        const float wy1 = iy - iy0f, wy0 = 1.0f - wy1;

        const int ix0 = (int)ix0f, iy0 = (int)iy0f;
        const int ix1 = ix0 + 1,   iy1 = iy0 + 1;

        const bool vx0 = (ix0 >= 0) & (ix0 <= W - 1);
        const bool vx1 = (ix1 >= 0) & (ix1 <= W - 1);
        const bool vy0 = (iy0 >= 0) & (iy0 <= H - 1);
        const bool vy1 = (iy1 >= 0) & (iy1 <= H - 1);

        const int cx0 = min(max(ix0, 0), W - 1);
        const int cx1 = min(max(ix1, 0), W - 1);
        const int cy0 = min(max(iy0, 0), H - 1);
        const int cy1 = min(max(iy1, 0), H - 1);

        const float w00 = (vy0 && vx0) ? wy0 * wx0 : 0.0f;
        const float w01 = (vy0 && vx1) ? wy0 * wx1 : 0.0f;
        const float w10 = (vy1 && vx0) ? wy1 * wx0 : 0.0f;
        const float w11 = (vy1 && vx1) ? wy1 * wx1 : 0.0f;

        const int o00 = cy0 * W + cx0;
        const int o01 = cy0 * W + cx1;
        const int o10 = cy1 * W + cx0;
        const int o11 = cy1 * W + cx1;

#pragma unroll
        for (int c = 0; c < C; ++c) {
            const float* p = img + (size_t)c * plane;
            float v = p[o00] * w00 + p[o01] * w01 + p[o10] * w10 + p[o11] * w11;
            __builtin_nontemporal_store(v, ob + (size_t)c * plane + (size_t)r * W);
        }
    }
}

extern "C" void kernel_launch(void* const* d_in, const int* in_sizes, int n_in,
                              void* d_out, int out_size, void* d_ws, size_t ws_size,
                              hipStream_t stream)
{
    const float* x     = (const float*)d_in[0];
    const float* usmp  = (const float*)d_in[1];
    const float* nsmp  = (const float*)d_in[2];
    const float* Wt    = (const float*)d_in[3];
    const float* bt    = (const float*)d_in[4];
    const int*   tsmp  = (const int*)d_in[5];
    const int*   distr = (const int*)d_in[6];
    float* out = (float*)d_out;

    dim3 grid(256 * (256 / 4));   // B * H/ROWS = 16384
    dim3 block(256);
    dataug_kernel<<<grid, block, 0, stream>>>(x, usmp, nsmp, Wt, bt, tsmp, distr, out);
}

// Round 4
// 390.725 us; speedup vs baseline: 1.0315x; 1.0187x over previous
//
#include <hip/hip_runtime.h>

// B=256, C=3, H=W=256, E=8
// out[b,c,h,w] = bilinear_sample(x[b,c], affine(theta_b, (h,w))), zero padding,
// align_corners=False. theta_b = smp_b * Wt[e] + bt[e], e = tsmp[b],
// smp_b = distr_flags[e]==1 ? nsmp[b] : usmp[b].
//
// R4: A/B isolation. R2/R3's XCD swizzle + NT stores made things SLOWER
// (156 -> 170us) despite 4x less HBM fetch -> suspected L2 hot-set
// contention (all CUs of an XCD sweeping the same image rows) and/or NT
// store policy loss. Revert both to R1's policy (natural block order,
// plain stores), KEEP the 4-rows-per-thread ILP from R3.

__global__ __launch_bounds__(256) void dataug_kernel(
    const float* __restrict__ x,
    const float* __restrict__ usmp,
    const float* __restrict__ nsmp,
    const float* __restrict__ Wt,
    const float* __restrict__ bt,
    const int*   __restrict__ tsmp,
    const int*   __restrict__ distr,
    float* __restrict__ out)
{
    constexpr int H = 256, W = 256, C = 3;
    constexpr int ROWS = 4;                       // rows per thread

    const int bh4 = blockIdx.x;                   // natural order (no swizzle)
    const int b  = bh4 >> 6;          // / (H/ROWS)
    const int h0 = (bh4 & 63) << 2;   // % (H/ROWS) * ROWS
    const int w  = threadIdx.x;

    // --- per-batch theta (block-uniform -> scalar loads) ---
    const int e = tsmp[b];
    const float smp = (distr[e] == 1) ? nsmp[b] : usmp[b];
    const float t0 = smp * Wt[e*6 + 0] + bt[e*6 + 0];
    const float t1 = smp * Wt[e*6 + 1] + bt[e*6 + 1];
    const float t2 = smp * Wt[e*6 + 2] + bt[e*6 + 2];
    const float t3 = smp * Wt[e*6 + 3] + bt[e*6 + 3];
    const float t4 = smp * Wt[e*6 + 4] + bt[e*6 + 4];
    const float t5 = smp * Wt[e*6 + 5] + bt[e*6 + 5];

    // --- affine grid (align_corners=False), row h0 ---
    const float xs = (2.0f * (float)w  + 1.0f) / (float)W - 1.0f;
    const float ys = (2.0f * (float)h0 + 1.0f) / (float)H - 1.0f;
    const float gx0 = t0 * xs + t1 * ys + t2;
    const float gy0 = t3 * xs + t4 * ys + t5;

    // unnormalized pixel coords for row h0; per-row step is (t1, t4)
    const float ix_base = ((gx0 + 1.0f) * (float)W - 1.0f) * 0.5f;
    const float iy_base = ((gy0 + 1.0f) * (float)H - 1.0f) * 0.5f;

    const size_t plane = (size_t)H * W;
    const float* img = x   + (size_t)b * C * plane;
    float*       ob  = out + (size_t)b * C * plane + (size_t)h0 * W + w;

#pragma unroll
    for (int r = 0; r < ROWS; ++r) {
        const float ix = ix_base + t1 * (float)r;
        const float iy = iy_base + t4 * (float)r;

        const float ix0f = floorf(ix);
        const float iy0f = floorf(iy);
        const float wx1 = ix - ix0f, wx0 = 1.0f - wx1;
        const float wy1 = iy - iy0f, wy0 = 1.0f - wy1;

        const int ix0 = (int)ix0f, iy0 = (int)iy0f;
        const int ix1 = ix0 + 1,   iy1 = iy0 + 1;

        const bool vx0 = (ix0 >= 0) & (ix0 <= W - 1);
        const bool vx1 = (ix1 >= 0) & (ix1 <= W - 1);
        const bool vy0 = (iy0 >= 0) & (iy0 <= H - 1);
        const bool vy1 = (iy1 >= 0) & (iy1 <= H - 1);

        const int cx0 = min(max(ix0, 0), W - 1);
        const int cx1 = min(max(ix1, 0), W - 1);
        const int cy0 = min(max(iy0, 0), H - 1);
        const int cy1 = min(max(iy1, 0), H - 1);

        const float w00 = (vy0 && vx0) ? wy0 * wx0 : 0.0f;
        const float w01 = (vy0 && vx1) ? wy0 * wx1 : 0.0f;
        const float w10 = (vy1 && vx0) ? wy1 * wx0 : 0.0f;
        const float w11 = (vy1 && vx1) ? wy1 * wx1 : 0.0f;

        const int o00 = cy0 * W + cx0;
        const int o01 = cy0 * W + cx1;
        const int o10 = cy1 * W + cx0;
        const int o11 = cy1 * W + cx1;

#pragma unroll
        for (int c = 0; c < C; ++c) {
            const float* p = img + (size_t)c * plane;
            float v = p[o00] * w00 + p[o01] * w01 + p[o10] * w10 + p[o11] * w11;
            ob[(size_t)c * plane + (size_t)r * W] = v;
        }
    }
}

extern "C" void kernel_launch(void* const* d_in, const int* in_sizes, int n_in,
                              void* d_out, int out_size, void* d_ws, size_t ws_size,
                              hipStream_t stream)
{
    const float* x     = (const float*)d_in[0];
    const float* usmp  = (const float*)d_in[1];
    const float* nsmp  = (const float*)d_in[2];
    const float* Wt    = (const float*)d_in[3];
    const float* bt    = (const float*)d_in[4];
    const int*   tsmp  = (const int*)d_in[5];
    const int*   distr = (const int*)d_in[6];
    float* out = (float*)d_out;

    dim3 grid(256 * (256 / 4));   // B * H/ROWS = 16384
    dim3 block(256);
    dataug_kernel<<<grid, block, 0, stream>>>(x, usmp, nsmp, Wt, bt, tsmp, distr, out);
}